// Round 3
// baseline (141.498 us; speedup 1.0000x reference)
//
#include <hip/hip_runtime.h>
#include <math.h>

// QuantumPolicy via MFMA:
//   qw is a fixed input => the whole circuit (CNOT rings + RY(qw) layers) is a
//   batch-independent 64x64 orthogonal matrix U. Per element we only need the
//   AngleEmbedding product state a[64], then out_state = a @ U^T  -> squared
//   probs -> Z expectations -> heads.
//
// kernel1 (1 wave): each lane simulates one basis state through the circuit
//   (precise sincosf), LDS-transpose, emit U as MFMA B-fragments, split into
//   exact hi+lo truncated-bf16 pairs (U = Uh + Ul bitwise-exact in fp32).
// kernel2 (512 blocks x 256): per wave-iteration of 64 elements:
//   MLP (fp32 VALU) -> product state -> split-bf16 A rows -> per-wave LDS ->
//   A-frags -> 3-way split MFMA (AhUh + AhUl + AlUh, err ~2^-17) -> squared
//   probs via LDS -> reduction tree -> softmax/value heads.
//   Per-wave LDS regions => no __syncthreads in the loop (DS in-order/wave).
//
// Fragment layouts (HW-verified per guide m89/m91/m118-122):
//   A: lane holds A[m=lane&15][k=(lane>>4)*8+j], j=0..7
//   B: lane holds B[k=(lane>>4)*8+j][n=lane&15]
//   C: lane holds C[row=(lane>>4)*4+reg][col=lane&15]

#define NQ 6
#define NL 4
#define NA 4
#define PD 64

typedef float v2 __attribute__((ext_vector_type(2)));
using bf16x8 = __attribute__((ext_vector_type(8))) short;
using f32x4  = __attribute__((ext_vector_type(4))) float;

__device__ __forceinline__ v2 mk2(float a, float b) { v2 r; r.x = a; r.y = b; return r; }
__device__ __forceinline__ v2 pkfma(v2 a, v2 b, v2 c) { return __builtin_elementwise_fma(a, b, c); }

// exact split: f = hi + lo with hi = truncate-to-bf16(f); returns packed bf16
// pairs (element 0 in low 16 bits). lo is itself bf16-truncated (residual 2^-17).
__device__ __forceinline__ void split2(float f0, float f1, unsigned int& hi, unsigned int& lo) {
    unsigned int u0 = __float_as_uint(f0), u1 = __float_as_uint(f1);
    unsigned int h0 = u0 & 0xFFFF0000u, h1 = u1 & 0xFFFF0000u;
    hi = (u0 >> 16) | h1;
    float l0 = f0 - __uint_as_float(h0);
    float l1 = f1 - __uint_as_float(h1);
    lo = (__float_as_uint(l0) >> 16) | (__float_as_uint(l1) & 0xFFFF0000u);
}

__device__ __forceinline__ bf16x8 as_bf16x8(uint4 u) {
    union { uint4 a; bf16x8 b; } c; c.a = u; return c.b;
}

// ---------------- kernel 1: build U fragments into d_ws ----------------
// ws layout: uint4 frag_hi[8][64] (8 KB) then uint4 frag_lo[8][64] (8 KB).
// frag index f = nt*2 + kb  (nt = n-tile 0..3, kb = k-block 0..1).
__global__ __launch_bounds__(64) void build_u_kernel(
    const float* __restrict__ qw, uint4* __restrict__ ufrag)
{
    __shared__ float Ut[64 * 68];   // U[j][e], row stride 68 dwords (bank-safe)
    const int e = threadIdx.x;      // basis state / column index

    float st[64];
#pragma unroll
    for (int k = 0; k < 64; ++k) st[k] = (k == e) ? 1.0f : 0.0f;

#pragma unroll
    for (int l = 0; l < NL; ++l) {
        // CNOT(i, (i+1)%6): compile-time register swaps
#pragma unroll
        for (int i = 0; i < NQ; ++i) {
            const int cm = 1 << (5 - i), tm = 1 << (5 - ((i + 1) % NQ));
#pragma unroll
            for (int idx = 0; idx < 64; ++idx) {
                if ((idx & cm) && !(idx & tm)) {
                    float t = st[idx]; st[idx] = st[idx | tm]; st[idx | tm] = t;
                }
            }
        }
        // RY(qw[l][i]) with precise sincos (runs once, accuracy matters)
#pragma unroll
        for (int i = 0; i < NQ; ++i) {
            const int qm = 1 << (5 - i);
            float sh, ch;
            sincosf(0.5f * qw[l * NQ + i], &sh, &ch);
#pragma unroll
            for (int idx = 0; idx < 64; ++idx) {
                if (!(idx & qm)) {
                    float a0 = st[idx], a1 = st[idx | qm];
                    st[idx]      = ch * a0 - sh * a1;
                    st[idx | qm] = ch * a1 + sh * a0;
                }
            }
        }
    }

    // st[j] = U[j][e]; transpose through LDS
#pragma unroll
    for (int j = 0; j < 64; ++j) Ut[j * 68 + e] = st[j];
    __syncthreads();

    const int c = e & 15, q = e >> 4;
#pragma unroll
    for (int f = 0; f < 8; ++f) {
        const int nt = f >> 1, kb = f & 1;
        float v[8];
#pragma unroll
        for (int j = 0; j < 8; ++j)
            v[j] = Ut[(16 * nt + c) * 68 + 32 * kb + 8 * q + j];   // U[n][k]
        uint4 hi, lo;
        split2(v[0], v[1], hi.x, lo.x);
        split2(v[2], v[3], hi.y, lo.y);
        split2(v[4], v[5], hi.z, lo.z);
        split2(v[6], v[7], hi.w, lo.w);
        ufrag[f * 64 + e]       = hi;
        ufrag[512 + f * 64 + e] = lo;
    }
}

// ---------------- kernel 2: main batched kernel ----------------
// Per-wave LDS region (18432 B): A_hi rows 64x144B, A_lo at +9216.
// Probs region reuses the same bytes: 64 rows x 272 B (17408 B).
#define WREG 18432

__global__ __launch_bounds__(256, 2) void qpolicy_mfma(
    const float* __restrict__ x,
    const float* __restrict__ W1,
    const float* __restrict__ b1,
    const float* __restrict__ W2,
    const float* __restrict__ b2,
    const float* __restrict__ Wp,
    const float* __restrict__ bp,
    const float* __restrict__ Wv,
    const float* __restrict__ bv,
    const uint4* __restrict__ ufrag,
    float* __restrict__ out,
    int B)
{
    __shared__ __align__(16) unsigned char smem[4 * WREG];
    const int lane = threadIdx.x & 63;
    const int wave = threadIdx.x >> 6;
    unsigned char* Ahi = smem + wave * WREG;
    unsigned char* Alo = Ahi + 9216;

    // U fragments (hi+lo), once per wave; 16 KB total, L2-resident.
    bf16x8 Uh[8], Ul[8];
#pragma unroll
    for (int f = 0; f < 8; ++f) {
        Uh[f] = as_bf16x8(ufrag[f * 64 + lane]);
        Ul[f] = as_bf16x8(ufrag[512 + f * 64 + lane]);
    }

    const v2* W1v = reinterpret_cast<const v2*>(W1);
    const v2* W2v = reinterpret_cast<const v2*>(W2);
    const int c15 = lane & 15, q4 = lane >> 4;

#pragma unroll 1
    for (int it = 0; it < 2; ++it) {
        const int elem = blockIdx.x * 512 + it * 256 + (int)threadIdx.x;

        // ---- load x, MLP (fp32 VALU; weights are wave-uniform s_loads)
        const v2* xv = reinterpret_cast<const v2*>(x + (size_t)elem * NQ);
        const v2 x01 = xv[0], x23 = xv[1], x45 = xv[2];

        v2 h2[PD / 2];
#pragma unroll
        for (int j2 = 0; j2 < PD / 2; ++j2) {
            float hj[2];
#pragma unroll
            for (int u = 0; u < 2; ++u) {
                const int j = 2 * j2 + u;
                v2 acc = mk2(b1[j], 0.0f);
                acc = pkfma(x01, W1v[j * 3 + 0], acc);
                acc = pkfma(x23, W1v[j * 3 + 1], acc);
                acc = pkfma(x45, W1v[j * 3 + 2], acc);
                hj[u] = fmaxf(acc.x + acc.y, 0.0f);
            }
            h2[j2] = mk2(hj[0], hj[1]);
        }
        float xp[NQ];
#pragma unroll
        for (int i = 0; i < NQ; ++i) {
            v2 acc = mk2(b2[i], 0.0f);
#pragma unroll
            for (int k = 0; k < PD / 2; ++k) acc = pkfma(h2[k], W2v[i * (PD / 2) + k], acc);
            xp[i] = fmaxf(acc.x + acc.y, 0.0f);
        }

        // ---- product state: pr[idx] = prod_q f_q(bit(5-q) of idx)
        float cq[NQ], sq[NQ];
#pragma unroll
        for (int q = 0; q < NQ; ++q) __sincosf(0.5f * xp[q], &sq[q], &cq[q]);
        float pr[64];
        pr[0] = 1.0f;
#pragma unroll
        for (int q = 0; q < NQ; ++q) {
            const int sz = 1 << q;
#pragma unroll
            for (int k = sz - 1; k >= 0; --k) {
                const float v = pr[k];
                pr[2 * k]     = v * cq[q];
                pr[2 * k + 1] = v * sq[q];
            }
        }

        // ---- split rows into hi/lo bf16, write to this wave's LDS region
#pragma unroll
        for (int w = 0; w < 8; ++w) {
            uint4 hi, lo;
            split2(pr[8 * w + 0], pr[8 * w + 1], hi.x, lo.x);
            split2(pr[8 * w + 2], pr[8 * w + 3], hi.y, lo.y);
            split2(pr[8 * w + 4], pr[8 * w + 5], hi.z, lo.z);
            split2(pr[8 * w + 6], pr[8 * w + 7], hi.w, lo.w);
            *reinterpret_cast<uint4*>(Ahi + lane * 144 + w * 16) = hi;
            *reinterpret_cast<uint4*>(Alo + lane * 144 + w * 16) = lo;
        }

        // ---- A fragments (DS ops are in-order per wave; compiler inserts waits)
        bf16x8 Ah[4][2], Al[4][2];
#pragma unroll
        for (int mt = 0; mt < 4; ++mt)
#pragma unroll
            for (int kb = 0; kb < 2; ++kb) {
                const int off = (16 * mt + c15) * 144 + kb * 64 + q4 * 16;
                Ah[mt][kb] = *reinterpret_cast<const bf16x8*>(Ahi + off);
                Al[mt][kb] = *reinterpret_cast<const bf16x8*>(Alo + off);
            }

        // ---- 3-way split MFMA: C = Ah*Uh + Ah*Ul + Al*Uh
        f32x4 C[4][4];
#pragma unroll
        for (int mt = 0; mt < 4; ++mt)
#pragma unroll
            for (int nt = 0; nt < 4; ++nt) C[mt][nt] = (f32x4){0.f, 0.f, 0.f, 0.f};
#pragma unroll
        for (int kb = 0; kb < 2; ++kb)
#pragma unroll
            for (int mt = 0; mt < 4; ++mt)
#pragma unroll
                for (int nt = 0; nt < 4; ++nt) {
                    const int f = nt * 2 + kb;
                    C[mt][nt] = __builtin_amdgcn_mfma_f32_16x16x32_bf16(Ah[mt][kb], Uh[f], C[mt][nt], 0, 0, 0);
                    C[mt][nt] = __builtin_amdgcn_mfma_f32_16x16x32_bf16(Ah[mt][kb], Ul[f], C[mt][nt], 0, 0, 0);
                    C[mt][nt] = __builtin_amdgcn_mfma_f32_16x16x32_bf16(Al[mt][kb], Uh[f], C[mt][nt], 0, 0, 0);
                }

        // ---- squared probs to LDS (reuse region; 272 B stride: 2-way banks)
#pragma unroll
        for (int mt = 0; mt < 4; ++mt)
#pragma unroll
            for (int nt = 0; nt < 4; ++nt)
#pragma unroll
                for (int r = 0; r < 4; ++r) {
                    const float vv = C[mt][nt][r];
                    const int row = 16 * mt + 4 * q4 + r;
                    const int col = 16 * nt + c15;
                    *reinterpret_cast<float*>(Ahi + row * 272 + col * 4) = vv * vv;
                }

        // ---- read own row back
        float pv[64];
#pragma unroll
        for (int w = 0; w < 16; ++w) {
            f32x4 t = *reinterpret_cast<const f32x4*>(Ahi + lane * 272 + w * 16);
            pv[4 * w + 0] = t[0]; pv[4 * w + 1] = t[1];
            pv[4 * w + 2] = t[2]; pv[4 * w + 3] = t[3];
        }

        // ---- Z expectations: shared partial-sum tree, z_j = 2*S_j - T
        float a32[32], S5 = 0.0f;
#pragma unroll
        for (int k = 0; k < 32; ++k) {
            a32[k] = pv[2 * k] + pv[2 * k + 1];
            S5 += pv[2 * k];
        }
        float S0 = 0.0f;
#pragma unroll
        for (int k = 0; k < 16; ++k) S0 += a32[k];
        float b16[16];
#pragma unroll
        for (int k = 0; k < 16; ++k) b16[k] = a32[k] + a32[k | 16];
        float S1 = 0.0f;
#pragma unroll
        for (int k = 0; k < 8; ++k) S1 += b16[k];
        float b8[8];
#pragma unroll
        for (int k = 0; k < 8; ++k) b8[k] = b16[k] + b16[k | 8];
        const float S2 = b8[0] + b8[1] + b8[2] + b8[3];
        float b4[4];
#pragma unroll
        for (int k = 0; k < 4; ++k) b4[k] = b8[k] + b8[k | 4];
        const float S3 = b4[0] + b4[1];
        float b2a[2];
        b2a[0] = b4[0] + b4[2];
        b2a[1] = b4[1] + b4[3];
        const float S4 = b2a[0];
        const float T = b2a[0] + b2a[1];

        float z[NQ];
        z[0] = fmaf(2.0f, S0, -T);
        z[1] = fmaf(2.0f, S1, -T);
        z[2] = fmaf(2.0f, S2, -T);
        z[3] = fmaf(2.0f, S3, -T);
        z[4] = fmaf(2.0f, S4, -T);
        z[5] = fmaf(2.0f, S5, -T);

        // ---- policy head: softmax(z @ Wp^T + bp)
        float logits[NA];
#pragma unroll
        for (int aidx = 0; aidx < NA; ++aidx) {
            float acc = bp[aidx];
#pragma unroll
            for (int q = 0; q < NQ; ++q) acc = fmaf(z[q], Wp[aidx * NQ + q], acc);
            logits[aidx] = acc;
        }
        float m = logits[0];
#pragma unroll
        for (int aidx = 1; aidx < NA; ++aidx) m = fmaxf(m, logits[aidx]);
        float e[NA], esum = 0.0f;
#pragma unroll
        for (int aidx = 0; aidx < NA; ++aidx) { e[aidx] = __expf(logits[aidx] - m); esum += e[aidx]; }
        const float inv = 1.0f / esum;

        if (elem < B) {
            float4 pol;
            pol.x = e[0] * inv; pol.y = e[1] * inv; pol.z = e[2] * inv; pol.w = e[3] * inv;
            reinterpret_cast<float4*>(out)[elem] = pol;       // policy (B,4)

            float v = bv[0];
#pragma unroll
            for (int q = 0; q < NQ; ++q) v = fmaf(z[q], Wv[q], v);
            out[(size_t)B * NA + elem] = v;                   // value (B,)
        }
    }
}

extern "C" void kernel_launch(void* const* d_in, const int* in_sizes, int n_in,
                              void* d_out, int out_size, void* d_ws, size_t ws_size,
                              hipStream_t stream) {
    const float* x  = (const float*)d_in[0];
    const float* W1 = (const float*)d_in[1];
    const float* b1 = (const float*)d_in[2];
    const float* W2 = (const float*)d_in[3];
    const float* b2 = (const float*)d_in[4];
    const float* qw = (const float*)d_in[5];
    const float* Wp = (const float*)d_in[6];
    const float* bp = (const float*)d_in[7];
    const float* Wv = (const float*)d_in[8];
    const float* bv = (const float*)d_in[9];
    float* out = (float*)d_out;

    const int B = in_sizes[0] / NQ;          // 262144

    hipLaunchKernelGGL(build_u_kernel, dim3(1), dim3(64), 0, stream,
                       qw, (uint4*)d_ws);
    hipLaunchKernelGGL(qpolicy_mfma, dim3((B + 511) / 512), dim3(256), 0, stream,
                       x, W1, b1, W2, b2, Wp, bp, Wv, bv,
                       (const uint4*)d_ws, out, B);
}

// Round 5
// 101.752 us; speedup vs baseline: 1.3906x; 1.3906x over previous
//
#include <hip/hip_runtime.h>
#include <math.h>

// QuantumPolicy via MFMA, spill-free fp16 edition.
//   qw fixed => circuit = constant 64x64 orthogonal U. Per element: MLP ->
//   product state a[64] -> a @ U^T (MFMA, fp16 A single + fp16 U hi/lo) ->
//   squared probs -> marginal tree -> softmax/value heads.
//
// kernel1 (1 wave): simulate 64 basis states (precise sincosf), emit U as
//   32x32x16 f16 B-fragments, exact hi+lo fp16 split, into d_ws (16 KB).
// kernel2 (1024 blocks x 256, 1 elem/thread): per-wave 8 KB LDS region,
//   128-B rows with chunk-XOR swizzle (c ^ (row&7)) -> ideal bank service for
//   row writes / A-frag reads / prob reads. Probs stored fp16 (values sum to
//   1 => relative rounding, total err <= 2.4e-4). No __syncthreads (per-wave
//   regions; DS ops are in-order per wave).
//
// 32x32x16 layouts (C verified m74/m101; A/B by the standard gfx950 mapping):
//   A: lane holds A[m=lane&31][k=8*(lane>>5)+j], j=0..7 (per 16-k block)
//   B: lane holds B[k=8*(lane>>5)+j][n=lane&31]
//   C: lane holds C[row=(reg&3)+8*(reg>>2)+4*(lane>>5)][col=lane&31]

#define NQ 6
#define NL 4
#define NA 4
#define PD 64

typedef float v2 __attribute__((ext_vector_type(2)));
typedef _Float16 f16x8 __attribute__((ext_vector_type(8)));
typedef __fp16 h2v __attribute__((ext_vector_type(2)));
typedef float f32x16 __attribute__((ext_vector_type(16)));

__device__ __forceinline__ v2 mk2(float a, float b) { v2 r; r.x = a; r.y = b; return r; }
__device__ __forceinline__ v2 pkfma(v2 a, v2 b, v2 c) { return __builtin_elementwise_fma(a, b, c); }
__device__ __forceinline__ f16x8 as_f16x8(uint4 u) { union { uint4 a; f16x8 b; } c; c.a = u; return c.b; }

// ---------------- kernel 1: build U fragments (fp16 hi/lo) into d_ws -------
// ws: uint4 hi[8][64] then uint4 lo[8][64]; frag f = nt*4+kb (nt<2, kb<4).
__global__ __launch_bounds__(64) void build_u_kernel(
    const float* __restrict__ qw, uint4* __restrict__ ufrag)
{
    __shared__ float Uall[64 * 65];   // Uall[j][e] = U[j][e], pitch 65
    const int e = threadIdx.x;

    float st[64];
#pragma unroll
    for (int k = 0; k < 64; ++k) st[k] = (k == e) ? 1.0f : 0.0f;

#pragma unroll
    for (int l = 0; l < NL; ++l) {
#pragma unroll
        for (int i = 0; i < NQ; ++i) {
            const int cm = 1 << (5 - i), tm = 1 << (5 - ((i + 1) % NQ));
#pragma unroll
            for (int idx = 0; idx < 64; ++idx) {
                if ((idx & cm) && !(idx & tm)) {
                    float t = st[idx]; st[idx] = st[idx | tm]; st[idx | tm] = t;
                }
            }
        }
#pragma unroll
        for (int i = 0; i < NQ; ++i) {
            const int qm = 1 << (5 - i);
            float sh, ch;
            sincosf(0.5f * qw[l * NQ + i], &sh, &ch);
#pragma unroll
            for (int idx = 0; idx < 64; ++idx) {
                if (!(idx & qm)) {
                    float a0 = st[idx], a1 = st[idx | qm];
                    st[idx]      = ch * a0 - sh * a1;
                    st[idx | qm] = ch * a1 + sh * a0;
                }
            }
        }
    }

#pragma unroll
    for (int j = 0; j < 64; ++j) Uall[j * 65 + e] = st[j];
    __syncthreads();

    const int n31 = e & 31, q1 = e >> 5;
#pragma unroll
    for (int nt = 0; nt < 2; ++nt)
#pragma unroll
        for (int kb = 0; kb < 4; ++kb) {
            const int f = nt * 4 + kb;
            const int n = 32 * nt + n31;
            const int k0 = 16 * kb + 8 * q1;
            union { _Float16 h[8]; uint4 u; } hi, lo;
#pragma unroll
            for (int j = 0; j < 8; ++j) {
                float v = Uall[n * 65 + k0 + j];     // B[k][n] = U[n][k]
                _Float16 hh = (_Float16)v;
                hi.h[j] = hh;
                lo.h[j] = (_Float16)(v - (float)hh);
            }
            ufrag[f * 64 + e]       = hi.u;
            ufrag[512 + f * 64 + e] = lo.u;
        }
}

// ---------------- kernel 2: main batched kernel ----------------------------
__global__ __launch_bounds__(256) void qpolicy_mfma(
    const float* __restrict__ x,
    const float* __restrict__ W1,
    const float* __restrict__ b1,
    const float* __restrict__ W2,
    const float* __restrict__ b2,
    const float* __restrict__ Wp,
    const float* __restrict__ bp,
    const float* __restrict__ Wv,
    const float* __restrict__ bv,
    const uint4* __restrict__ ufrag,
    float* __restrict__ out,
    int B)
{
    __shared__ __align__(16) unsigned char smem[4 * 8192];
    const int tid = threadIdx.x, lane = tid & 63, wave = tid >> 6;
    unsigned char* base = smem + wave * 8192;
    const int L7 = lane & 7, q1 = lane >> 5, c31 = lane & 31;

    // Per-lane LDS pointers (all 16-aligned except pwp which is 2-aligned).
    unsigned char* wptr[8];                       // own row, logical chunk c
#pragma unroll
    for (int c = 0; c < 8; ++c) wptr[c] = base + 128 * lane + 16 * (c ^ L7);
    unsigned char* aptr[2][4];                    // A-frag (mt, kb)
#pragma unroll
    for (int mt = 0; mt < 2; ++mt)
#pragma unroll
        for (int kb = 0; kb < 4; ++kb)
            aptr[mt][kb] = base + 128 * (c31 + 32 * mt) + 16 * ((2 * kb + q1) ^ L7);
    unsigned char* pwp[2][4];                     // prob-write (nt, j=reg&3)
#pragma unroll
    for (int nt = 0; nt < 2; ++nt)
#pragma unroll
        for (int j = 0; j < 4; ++j) {
            const int m7 = 4 * q1 + j;            // (elem & 7) for this reg
            pwp[nt][j] = base + 128 * m7 + 16 * ((4 * nt + (c31 >> 3)) ^ m7)
                       + 2 * (c31 & 7);
        }

    const int elem = blockIdx.x * 256 + tid;

    // ---- load x (stride 24 B, 8-aligned -> 3x b64)
    const v2* xv = reinterpret_cast<const v2*>(x + (size_t)elem * NQ);
    const v2 x01 = xv[0], x23 = xv[1], x45 = xv[2];

    const v2* W1v = reinterpret_cast<const v2*>(W1);
    const v2* W2v = reinterpret_cast<const v2*>(W2);

    // ---- MLP1: h = relu(x @ W1^T + b1)
    v2 h2[PD / 2];
#pragma unroll
    for (int j2 = 0; j2 < PD / 2; ++j2) {
        float hj[2];
#pragma unroll
        for (int u = 0; u < 2; ++u) {
            const int j = 2 * j2 + u;
            v2 acc = mk2(b1[j], 0.0f);
            acc = pkfma(x01, W1v[j * 3 + 0], acc);
            acc = pkfma(x23, W1v[j * 3 + 1], acc);
            acc = pkfma(x45, W1v[j * 3 + 2], acc);
            hj[u] = fmaxf(acc.x + acc.y, 0.0f);
        }
        h2[j2] = mk2(hj[0], hj[1]);
    }
    // ---- MLP2: xp = relu(h @ W2^T + b2)
    float xp[NQ];
#pragma unroll
    for (int i = 0; i < NQ; ++i) {
        v2 acc = mk2(b2[i], 0.0f);
#pragma unroll
        for (int k = 0; k < PD / 2; ++k) acc = pkfma(h2[k], W2v[i * (PD / 2) + k], acc);
        xp[i] = fmaxf(acc.x + acc.y, 0.0f);
    }

    // ---- U fragments (L2-resident 16 KB; loaded after MLP to limit lifetimes)
    uint4 uh[8], ul[8];
#pragma unroll
    for (int f = 0; f < 8; ++f) {
        uh[f] = ufrag[f * 64 + lane];
        ul[f] = ufrag[512 + f * 64 + lane];
    }

    // ---- product state as P (qubits 0-2, state bits 5..3) x Q (qubits 3-5)
    float cq[NQ], sq[NQ];
#pragma unroll
    for (int q = 0; q < NQ; ++q) __sincosf(0.5f * xp[q], &sq[q], &cq[q]);

    float P[8], Q[8];
    P[0] = 1.0f; Q[0] = 1.0f;
#pragma unroll
    for (int q = 0; q < 3; ++q) {
        const int sz = 1 << q;
#pragma unroll
        for (int k = sz - 1; k >= 0; --k) {
            const float vp = P[k], vq = Q[k];
            P[2 * k] = vp * cq[q];     P[2 * k + 1] = vp * sq[q];
            Q[2 * k] = vq * cq[3 + q]; Q[2 * k + 1] = vq * sq[3 + q];
        }
    }

    // ---- write own pr row (fp16): chunk c holds states 8c..8c+7 = P[c]*Q[:]
    h2v qh[4];
#pragma unroll
    for (int t = 0; t < 4; ++t) qh[t] = __builtin_amdgcn_cvt_pkrtz(Q[2 * t], Q[2 * t + 1]);
#pragma unroll
    for (int c = 0; c < 8; ++c) {
        h2v ph = __builtin_amdgcn_cvt_pkrtz(P[c], P[c]);
        union { h2v h[4]; uint4 u; } row;
#pragma unroll
        for (int t = 0; t < 4; ++t) row.h[t] = ph * qh[t];
        *reinterpret_cast<uint4*>(wptr[c]) = row.u;
    }

    // ---- A fragments (in-order DS per wave; compiler inserts lgkm waits)
    f16x8 A[2][4];
#pragma unroll
    for (int mt = 0; mt < 2; ++mt)
#pragma unroll
        for (int kb = 0; kb < 4; ++kb)
            A[mt][kb] = *reinterpret_cast<const f16x8*>(aptr[mt][kb]);

    // ---- 2-pass MFMA: C = A*Uh + A*Ul  (U exact in hi+lo fp16)
    f32x16 C[2][2];
#pragma unroll
    for (int mt = 0; mt < 2; ++mt)
#pragma unroll
        for (int nt = 0; nt < 2; ++nt)
#pragma unroll
            for (int r = 0; r < 16; ++r) C[mt][nt][r] = 0.0f;
#pragma unroll
    for (int kb = 0; kb < 4; ++kb)
#pragma unroll
        for (int mt = 0; mt < 2; ++mt)
#pragma unroll
            for (int nt = 0; nt < 2; ++nt) {
                C[mt][nt] = __builtin_amdgcn_mfma_f32_32x32x16_f16(
                    A[mt][kb], as_f16x8(uh[nt * 4 + kb]), C[mt][nt], 0, 0, 0);
                C[mt][nt] = __builtin_amdgcn_mfma_f32_32x32x16_f16(
                    A[mt][kb], as_f16x8(ul[nt * 4 + kb]), C[mt][nt], 0, 0, 0);
            }

    // ---- squared probs -> fp16 -> LDS (region reuse; elem rows disjoint by mt)
#pragma unroll
    for (int mt = 0; mt < 2; ++mt)
#pragma unroll
        for (int nt = 0; nt < 2; ++nt)
#pragma unroll
            for (int r = 0; r < 16; ++r) {
                const float v = C[mt][nt][r];
                *reinterpret_cast<_Float16*>(pwp[nt][r & 3] + 1024 * (r >> 2) + 4096 * mt)
                    = (_Float16)(v * v);
            }

    // ---- read own prob row, unpack to fp32
    float pv[64];
#pragma unroll
    for (int c = 0; c < 8; ++c) {
        union { uint4 u; _Float16 h[8]; } rb;
        rb.u = *reinterpret_cast<const uint4*>(wptr[c]);
#pragma unroll
        for (int i = 0; i < 8; ++i) pv[8 * c + i] = (float)rb.h[i];
    }

    // ---- Z expectations: shared partial-sum tree, z_j = 2*S_j - T
    float a32[32], S5 = 0.0f;
#pragma unroll
    for (int k = 0; k < 32; ++k) {
        a32[k] = pv[2 * k] + pv[2 * k + 1];
        S5 += pv[2 * k];
    }
    float S0 = 0.0f;
#pragma unroll
    for (int k = 0; k < 16; ++k) S0 += a32[k];
    float b16a[16];
#pragma unroll
    for (int k = 0; k < 16; ++k) b16a[k] = a32[k] + a32[k | 16];
    float S1 = 0.0f;
#pragma unroll
    for (int k = 0; k < 8; ++k) S1 += b16a[k];
    float b8[8];
#pragma unroll
    for (int k = 0; k < 8; ++k) b8[k] = b16a[k] + b16a[k | 8];
    const float S2 = b8[0] + b8[1] + b8[2] + b8[3];
    float b4[4];
#pragma unroll
    for (int k = 0; k < 4; ++k) b4[k] = b8[k] + b8[k | 4];
    const float S3 = b4[0] + b4[1];
    float b2a[2];
    b2a[0] = b4[0] + b4[2];
    b2a[1] = b4[1] + b4[3];
    const float S4 = b2a[0];
    const float T = b2a[0] + b2a[1];

    float z[NQ];
    z[0] = fmaf(2.0f, S0, -T);
    z[1] = fmaf(2.0f, S1, -T);
    z[2] = fmaf(2.0f, S2, -T);
    z[3] = fmaf(2.0f, S3, -T);
    z[4] = fmaf(2.0f, S4, -T);
    z[5] = fmaf(2.0f, S5, -T);

    // ---- policy head: softmax(z @ Wp^T + bp)
    float logits[NA];
#pragma unroll
    for (int a = 0; a < NA; ++a) {
        float acc = bp[a];
#pragma unroll
        for (int q = 0; q < NQ; ++q) acc = fmaf(z[q], Wp[a * NQ + q], acc);
        logits[a] = acc;
    }
    float m = logits[0];
#pragma unroll
    for (int a = 1; a < NA; ++a) m = fmaxf(m, logits[a]);
    float e[NA], esum = 0.0f;
#pragma unroll
    for (int a = 0; a < NA; ++a) { e[a] = __expf(logits[a] - m); esum += e[a]; }
    const float inv = 1.0f / esum;

    float4 pol;
    pol.x = e[0] * inv; pol.y = e[1] * inv; pol.z = e[2] * inv; pol.w = e[3] * inv;
    reinterpret_cast<float4*>(out)[elem] = pol;       // policy (B,4)

    float v = bv[0];
#pragma unroll
    for (int q = 0; q < NQ; ++q) v = fmaf(z[q], Wv[q], v);
    out[(size_t)B * NA + elem] = v;                   // value (B,)
}

extern "C" void kernel_launch(void* const* d_in, const int* in_sizes, int n_in,
                              void* d_out, int out_size, void* d_ws, size_t ws_size,
                              hipStream_t stream) {
    const float* x  = (const float*)d_in[0];
    const float* W1 = (const float*)d_in[1];
    const float* b1 = (const float*)d_in[2];
    const float* W2 = (const float*)d_in[3];
    const float* b2 = (const float*)d_in[4];
    const float* qw = (const float*)d_in[5];
    const float* Wp = (const float*)d_in[6];
    const float* bp = (const float*)d_in[7];
    const float* Wv = (const float*)d_in[8];
    const float* bv = (const float*)d_in[9];
    float* out = (float*)d_out;

    const int B = in_sizes[0] / NQ;          // 262144

    hipLaunchKernelGGL(build_u_kernel, dim3(1), dim3(64), 0, stream,
                       qw, (uint4*)d_ws);
    hipLaunchKernelGGL(qpolicy_mfma, dim3(B / 256), dim3(256), 0, stream,
                       x, W1, b1, W2, b2, Wp, bp, Wv, bv,
                       (const uint4*)d_ws, out, B);
}

// Round 6
// 99.729 us; speedup vs baseline: 1.4188x; 1.0203x over previous
//
#include <hip/hip_runtime.h>
#include <math.h>

// QuantumPolicy via MFMA, spill-free fp16 edition.
//   qw fixed => circuit = constant 64x64 orthogonal U. Per element: MLP ->
//   product state a[64] -> a @ U^T (MFMA, fp16 A single + fp16 U hi/lo) ->
//   squared probs -> marginal tree -> softmax/value heads.
//
// kernel1 (1 wave): simulate 64 basis states, emit U as 32x32x16 f16
//   B-fragments, exact hi+lo fp16 split, into d_ws (16 KB).
//   __launch_bounds__(64,1) + __sincosf keep st[64] register-resident
//   (round-5 post-mortem: default occupancy target spilled it -> 82 us).
// kernel2 (1024 blocks x 256, 1 elem/thread): per-wave 8 KB LDS region,
//   128-B rows with chunk-XOR swizzle (c ^ (row&7)) -> ideal bank service for
//   row writes / A-frag reads / prob reads. Probs stored fp16 (values sum to
//   1 => relative rounding, total err <= 2.4e-4). No __syncthreads (per-wave
//   regions; DS ops are in-order per wave).
//
// 32x32x16 layouts (C verified m74/m101; A/B by the standard gfx950 mapping):
//   A: lane holds A[m=lane&31][k=8*(lane>>5)+j], j=0..7 (per 16-k block)
//   B: lane holds B[k=8*(lane>>5)+j][n=lane&31]
//   C: lane holds C[row=(reg&3)+8*(reg>>2)+4*(lane>>5)][col=lane&31]

#define NQ 6
#define NL 4
#define NA 4
#define PD 64

typedef float v2 __attribute__((ext_vector_type(2)));
typedef _Float16 f16x8 __attribute__((ext_vector_type(8)));
typedef __fp16 h2v __attribute__((ext_vector_type(2)));
typedef float f32x16 __attribute__((ext_vector_type(16)));

__device__ __forceinline__ v2 mk2(float a, float b) { v2 r; r.x = a; r.y = b; return r; }
__device__ __forceinline__ v2 pkfma(v2 a, v2 b, v2 c) { return __builtin_elementwise_fma(a, b, c); }
__device__ __forceinline__ f16x8 as_f16x8(uint4 u) { union { uint4 a; f16x8 b; } c; c.a = u; return c.b; }

// ---------------- kernel 1: build U fragments (fp16 hi/lo) into d_ws -------
// ws: uint4 hi[8][64] then uint4 lo[8][64]; frag f = nt*4+kb (nt<2, kb<4).
__global__ __launch_bounds__(64, 1) void build_u_kernel(
    const float* __restrict__ qw, uint4* __restrict__ ufrag)
{
    __shared__ float Uall[64 * 65];   // Uall[j][e] = U[j][e], pitch 65
    const int e = threadIdx.x;

    float st[64];
#pragma unroll
    for (int k = 0; k < 64; ++k) st[k] = (k == e) ? 1.0f : 0.0f;

#pragma unroll
    for (int l = 0; l < NL; ++l) {
#pragma unroll
        for (int i = 0; i < NQ; ++i) {
            const int cm = 1 << (5 - i), tm = 1 << (5 - ((i + 1) % NQ));
#pragma unroll
            for (int idx = 0; idx < 64; ++idx) {
                if ((idx & cm) && !(idx & tm)) {
                    float t = st[idx]; st[idx] = st[idx | tm]; st[idx | tm] = t;
                }
            }
        }
#pragma unroll
        for (int i = 0; i < NQ; ++i) {
            const int qm = 1 << (5 - i);
            float sh, ch;
            __sincosf(0.5f * qw[l * NQ + i], &sh, &ch);   // inline v_sin/v_cos
#pragma unroll
            for (int idx = 0; idx < 64; ++idx) {
                if (!(idx & qm)) {
                    float a0 = st[idx], a1 = st[idx | qm];
                    st[idx]      = ch * a0 - sh * a1;
                    st[idx | qm] = ch * a1 + sh * a0;
                }
            }
        }
    }

#pragma unroll
    for (int j = 0; j < 64; ++j) Uall[j * 65 + e] = st[j];
    __syncthreads();

    const int n31 = e & 31, q1 = e >> 5;
#pragma unroll
    for (int nt = 0; nt < 2; ++nt)
#pragma unroll
        for (int kb = 0; kb < 4; ++kb) {
            const int f = nt * 4 + kb;
            const int n = 32 * nt + n31;
            const int k0 = 16 * kb + 8 * q1;
            union { _Float16 h[8]; uint4 u; } hi, lo;
#pragma unroll
            for (int j = 0; j < 8; ++j) {
                float v = Uall[n * 65 + k0 + j];     // B[k][n] = U[n][k]
                _Float16 hh = (_Float16)v;
                hi.h[j] = hh;
                lo.h[j] = (_Float16)(v - (float)hh);
            }
            ufrag[f * 64 + e]       = hi.u;
            ufrag[512 + f * 64 + e] = lo.u;
        }
}

// ---------------- kernel 2: main batched kernel ----------------------------
__global__ __launch_bounds__(256) void qpolicy_mfma(
    const float* __restrict__ x,
    const float* __restrict__ W1,
    const float* __restrict__ b1,
    const float* __restrict__ W2,
    const float* __restrict__ b2,
    const float* __restrict__ Wp,
    const float* __restrict__ bp,
    const float* __restrict__ Wv,
    const float* __restrict__ bv,
    const uint4* __restrict__ ufrag,
    float* __restrict__ out,
    int B)
{
    __shared__ __align__(16) unsigned char smem[4 * 8192];
    const int tid = threadIdx.x, lane = tid & 63, wave = tid >> 6;
    unsigned char* base = smem + wave * 8192;
    const int L7 = lane & 7, q1 = lane >> 5, c31 = lane & 31;

    // Per-lane LDS pointers (all 16-aligned except pwp which is 2-aligned).
    unsigned char* wptr[8];                       // own row, logical chunk c
#pragma unroll
    for (int c = 0; c < 8; ++c) wptr[c] = base + 128 * lane + 16 * (c ^ L7);
    unsigned char* aptr[2][4];                    // A-frag (mt, kb)
#pragma unroll
    for (int mt = 0; mt < 2; ++mt)
#pragma unroll
        for (int kb = 0; kb < 4; ++kb)
            aptr[mt][kb] = base + 128 * (c31 + 32 * mt) + 16 * ((2 * kb + q1) ^ L7);
    unsigned char* pwp[2][4];                     // prob-write (nt, j=reg&3)
#pragma unroll
    for (int nt = 0; nt < 2; ++nt)
#pragma unroll
        for (int j = 0; j < 4; ++j) {
            const int m7 = 4 * q1 + j;            // (elem & 7) for this reg
            pwp[nt][j] = base + 128 * m7 + 16 * ((4 * nt + (c31 >> 3)) ^ m7)
                       + 2 * (c31 & 7);
        }

    const int elem = blockIdx.x * 256 + tid;

    // ---- load x (stride 24 B, 8-aligned -> 3x b64)
    const v2* xv = reinterpret_cast<const v2*>(x + (size_t)elem * NQ);
    const v2 x01 = xv[0], x23 = xv[1], x45 = xv[2];

    const v2* W1v = reinterpret_cast<const v2*>(W1);
    const v2* W2v = reinterpret_cast<const v2*>(W2);

    // ---- MLP1: h = relu(x @ W1^T + b1)
    v2 h2[PD / 2];
#pragma unroll
    for (int j2 = 0; j2 < PD / 2; ++j2) {
        float hj[2];
#pragma unroll
        for (int u = 0; u < 2; ++u) {
            const int j = 2 * j2 + u;
            v2 acc = mk2(b1[j], 0.0f);
            acc = pkfma(x01, W1v[j * 3 + 0], acc);
            acc = pkfma(x23, W1v[j * 3 + 1], acc);
            acc = pkfma(x45, W1v[j * 3 + 2], acc);
            hj[u] = fmaxf(acc.x + acc.y, 0.0f);
        }
        h2[j2] = mk2(hj[0], hj[1]);
    }
    // ---- MLP2: xp = relu(h @ W2^T + b2)
    float xp[NQ];
#pragma unroll
    for (int i = 0; i < NQ; ++i) {
        v2 acc = mk2(b2[i], 0.0f);
#pragma unroll
        for (int k = 0; k < PD / 2; ++k) acc = pkfma(h2[k], W2v[i * (PD / 2) + k], acc);
        xp[i] = fmaxf(acc.x + acc.y, 0.0f);
    }

    // ---- U fragments (L2-resident 16 KB; loaded after MLP to limit lifetimes)
    uint4 uh[8], ul[8];
#pragma unroll
    for (int f = 0; f < 8; ++f) {
        uh[f] = ufrag[f * 64 + lane];
        ul[f] = ufrag[512 + f * 64 + lane];
    }

    // ---- product state as P (qubits 0-2, state bits 5..3) x Q (qubits 3-5)
    float cq[NQ], sq[NQ];
#pragma unroll
    for (int q = 0; q < NQ; ++q) __sincosf(0.5f * xp[q], &sq[q], &cq[q]);

    float P[8], Q[8];
    P[0] = 1.0f; Q[0] = 1.0f;
#pragma unroll
    for (int q = 0; q < 3; ++q) {
        const int sz = 1 << q;
#pragma unroll
        for (int k = sz - 1; k >= 0; --k) {
            const float vp = P[k], vq = Q[k];
            P[2 * k] = vp * cq[q];     P[2 * k + 1] = vp * sq[q];
            Q[2 * k] = vq * cq[3 + q]; Q[2 * k + 1] = vq * sq[3 + q];
        }
    }

    // ---- write own pr row (fp16): chunk c holds states 8c..8c+7 = P[c]*Q[:]
    h2v qh[4];
#pragma unroll
    for (int t = 0; t < 4; ++t) qh[t] = __builtin_amdgcn_cvt_pkrtz(Q[2 * t], Q[2 * t + 1]);
#pragma unroll
    for (int c = 0; c < 8; ++c) {
        h2v ph = __builtin_amdgcn_cvt_pkrtz(P[c], P[c]);
        union { h2v h[4]; uint4 u; } row;
#pragma unroll
        for (int t = 0; t < 4; ++t) row.h[t] = ph * qh[t];
        *reinterpret_cast<uint4*>(wptr[c]) = row.u;
    }

    // ---- A fragments (in-order DS per wave; compiler inserts lgkm waits)
    f16x8 A[2][4];
#pragma unroll
    for (int mt = 0; mt < 2; ++mt)
#pragma unroll
        for (int kb = 0; kb < 4; ++kb)
            A[mt][kb] = *reinterpret_cast<const f16x8*>(aptr[mt][kb]);

    // ---- 2-pass MFMA: C = A*Uh + A*Ul  (U exact in hi+lo fp16)
    f32x16 C[2][2];
#pragma unroll
    for (int mt = 0; mt < 2; ++mt)
#pragma unroll
        for (int nt = 0; nt < 2; ++nt)
#pragma unroll
            for (int r = 0; r < 16; ++r) C[mt][nt][r] = 0.0f;
#pragma unroll
    for (int kb = 0; kb < 4; ++kb)
#pragma unroll
        for (int mt = 0; mt < 2; ++mt)
#pragma unroll
            for (int nt = 0; nt < 2; ++nt) {
                C[mt][nt] = __builtin_amdgcn_mfma_f32_32x32x16_f16(
                    A[mt][kb], as_f16x8(uh[nt * 4 + kb]), C[mt][nt], 0, 0, 0);
                C[mt][nt] = __builtin_amdgcn_mfma_f32_32x32x16_f16(
                    A[mt][kb], as_f16x8(ul[nt * 4 + kb]), C[mt][nt], 0, 0, 0);
            }

    // ---- squared probs -> fp16 -> LDS (region reuse; elem rows disjoint by mt)
#pragma unroll
    for (int mt = 0; mt < 2; ++mt)
#pragma unroll
        for (int nt = 0; nt < 2; ++nt)
#pragma unroll
            for (int r = 0; r < 16; ++r) {
                const float v = C[mt][nt][r];
                *reinterpret_cast<_Float16*>(pwp[nt][r & 3] + 1024 * (r >> 2) + 4096 * mt)
                    = (_Float16)(v * v);
            }

    // ---- read own prob row, unpack to fp32
    float pv[64];
#pragma unroll
    for (int c = 0; c < 8; ++c) {
        union { uint4 u; _Float16 h[8]; } rb;
        rb.u = *reinterpret_cast<const uint4*>(wptr[c]);
#pragma unroll
        for (int i = 0; i < 8; ++i) pv[8 * c + i] = (float)rb.h[i];
    }

    // ---- Z expectations: shared partial-sum tree, z_j = 2*S_j - T
    float a32[32], S5 = 0.0f;
#pragma unroll
    for (int k = 0; k < 32; ++k) {
        a32[k] = pv[2 * k] + pv[2 * k + 1];
        S5 += pv[2 * k];
    }
    float S0 = 0.0f;
#pragma unroll
    for (int k = 0; k < 16; ++k) S0 += a32[k];
    float b16a[16];
#pragma unroll
    for (int k = 0; k < 16; ++k) b16a[k] = a32[k] + a32[k | 16];
    float S1 = 0.0f;
#pragma unroll
    for (int k = 0; k < 8; ++k) S1 += b16a[k];
    float b8[8];
#pragma unroll
    for (int k = 0; k < 8; ++k) b8[k] = b16a[k] + b16a[k | 8];
    const float S2 = b8[0] + b8[1] + b8[2] + b8[3];
    float b4[4];
#pragma unroll
    for (int k = 0; k < 4; ++k) b4[k] = b8[k] + b8[k | 4];
    const float S3 = b4[0] + b4[1];
    float b2a[2];
    b2a[0] = b4[0] + b4[2];
    b2a[1] = b4[1] + b4[3];
    const float S4 = b2a[0];
    const float T = b2a[0] + b2a[1];

    float z[NQ];
    z[0] = fmaf(2.0f, S0, -T);
    z[1] = fmaf(2.0f, S1, -T);
    z[2] = fmaf(2.0f, S2, -T);
    z[3] = fmaf(2.0f, S3, -T);
    z[4] = fmaf(2.0f, S4, -T);
    z[5] = fmaf(2.0f, S5, -T);

    // ---- policy head: softmax(z @ Wp^T + bp)
    float logits[NA];
#pragma unroll
    for (int a = 0; a < NA; ++a) {
        float acc = bp[a];
#pragma unroll
        for (int q = 0; q < NQ; ++q) acc = fmaf(z[q], Wp[a * NQ + q], acc);
        logits[a] = acc;
    }
    float m = logits[0];
#pragma unroll
    for (int a = 1; a < NA; ++a) m = fmaxf(m, logits[a]);
    float e[NA], esum = 0.0f;
#pragma unroll
    for (int a = 0; a < NA; ++a) { e[a] = __expf(logits[a] - m); esum += e[a]; }
    const float inv = 1.0f / esum;

    float4 pol;
    pol.x = e[0] * inv; pol.y = e[1] * inv; pol.z = e[2] * inv; pol.w = e[3] * inv;
    reinterpret_cast<float4*>(out)[elem] = pol;       // policy (B,4)

    float v = bv[0];
#pragma unroll
    for (int q = 0; q < NQ; ++q) v = fmaf(z[q], Wv[q], v);
    out[(size_t)B * NA + elem] = v;                   // value (B,)
}

extern "C" void kernel_launch(void* const* d_in, const int* in_sizes, int n_in,
                              void* d_out, int out_size, void* d_ws, size_t ws_size,
                              hipStream_t stream) {
    const float* x  = (const float*)d_in[0];
    const float* W1 = (const float*)d_in[1];
    const float* b1 = (const float*)d_in[2];
    const float* W2 = (const float*)d_in[3];
    const float* b2 = (const float*)d_in[4];
    const float* qw = (const float*)d_in[5];
    const float* Wp = (const float*)d_in[6];
    const float* bp = (const float*)d_in[7];
    const float* Wv = (const float*)d_in[8];
    const float* bv = (const float*)d_in[9];
    float* out = (float*)d_out;

    const int B = in_sizes[0] / NQ;          // 262144

    hipLaunchKernelGGL(build_u_kernel, dim3(1), dim3(64), 0, stream,
                       qw, (uint4*)d_ws);
    hipLaunchKernelGGL(qpolicy_mfma, dim3(B / 256), dim3(256), 0, stream,
                       x, W1, b1, W2, b2, Wp, bp, Wv, bv,
                       (const uint4*)d_ws, out, B);
}